// Round 16
// baseline (73.877 us; speedup 1.0000x reference)
//
#include <hip/hip_runtime.h>

// GradientCurvatureAttention: fused depthwise-conv + curvature + channel-softmax + scale.
// x: [B=16, C=128, H=128, W=128] fp32, NCHW. out: same shape.
//
// Round 16: R15 (57.8us) with CGRP flipped 8->16 (CPW=8, block (32,16)=512):
// per-thread arrays halve (s[8]+xc[8] = 32 f32) -> VGPR ~70 -> ~2x resident
// waves. Tests the latency-bound/occupancy diagnosis (R15: occ 20%, VALU 37%,
// HBM 3.4 TB/s). Keeps: xc-in-regs, NT stores, raw intrinsics, straight-line
// body, XCD swizzle.

#define GCA_B 16
#define GCA_C 128
#define GCA_H 128
#define GCA_W 128
#define CGRP  16           // channel groups (blockDim.y)
#define CPW   (GCA_C/CGRP) // 8 channels per group

#define GCA_LOG2E 1.44269504088896f

typedef float gca_f4 __attribute__((ext_vector_type(4)));  // native vec for NT store

__device__ __forceinline__ float gca_score16(float cpl, float cpc, float cpr,
                                             float cml, float cmc, float cmr,
                                             float cyl, float cyc, float cyr) {
    const float Gx  = cpl - cpr;                       // [1,2,1]v x [1,0,-1]h
    const float Gy  = fmaf(2.f, cmc, cml + cmr);       // [1,0,-1]v x [1,2,1]h
    const float Ixx = fmaf(-2.f, cpc, cpl + cpr);      // [1,2,1]v x [1,-2,1]h
    const float Ixy = cmr - cml;                       // [1,0,-1]v x [-1,0,1]h
    const float Iyy = fmaf(2.f, cyc, cyl + cyr);       // [1,-2,1]v x [1,2,1]h
    const float gy2 = Gy * Gy;
    const float g2e = fmaf(Gx, Gx, gy2 + 1e-6f);
    const float r   = __builtin_amdgcn_rsqf(g2e);      // raw v_rsq_f32
    const float gm  = g2e * r;                         // sqrt(g2e)
    const float t   = Gx * Iyy;
    const float p   = Gy * Ixy;
    const float inner = fmaf(-2.f, p, t);              // Gx*Iyy - 2*Gy*Ixy
    const float q   = gy2 * Ixx;
    const float num = fmaf(Gx, inner, q);
    const float r3  = (r * r) * r;
    return fmaf(num, r3, gm);                          // grad_mag + curvature
}

__global__ __launch_bounds__(512) void gca_fused16(const float* __restrict__ x,
                                                   float* __restrict__ out) {
    const int tx = threadIdx.x;                 // 0..31 : pixel quad, w0 = 4*tx
    const int ty = threadIdx.y;                 // 0..15 : channel group

    // XCD swizzle: 2048 blocks (= B*H, h minor), 256 consecutive ids per XCD.
    const int id  = blockIdx.x;
    const int swz = ((id & 7) << 8) | (id >> 3);
    const int h   = swz & 127;
    const int b   = swz >> 7;

    const int w0 = tx * 4;
    const int c0 = ty * CPW;

    const int hm = (h > 0) ? h - 1 : 0;
    const int hp = (h < GCA_H - 1) ? h + 1 : GCA_H - 1;
    const float mh0 = (h > 0) ? 1.f : 0.f;
    const float mh2 = (h < GCA_H - 1) ? 1.f : 0.f;
    const float mwA = (tx > 0) ? 1.f : 0.f;    // left halo exists
    const float mwB = (tx < 31) ? 1.f : 0.f;   // right halo exists

    const size_t plane = (size_t)GCA_H * GCA_W;
    const float* base = x   + ((size_t)b * GCA_C + c0) * plane;
    float* obase      = out + ((size_t)b * GCA_C + c0) * plane;

    const int r0off = hm * GCA_W + w0;
    const int r1off = h  * GCA_W + w0;
    const int r2off = hp * GCA_W + w0;

    float4 s[CPW];                       // scores, then exp values
    float4 xc[CPW];                      // center row, kept for the epilogue
    float4 lmax = make_float4(-3.0e38f, -3.0e38f, -3.0e38f, -3.0e38f);

    // Pass 1: conv + curvature scores for 4 pixels x 8 channels.
    #pragma unroll
    for (int i = 0; i < CPW; ++i) {
        const float* p = base + (size_t)i * plane;
        float4 v0 = *(const float4*)(p + r0off);
        const float4 v1 = *(const float4*)(p + r1off);
        float4 v2 = *(const float4*)(p + r2off);
        xc[i] = v1;

        // Row-edge masks (identity except h=0 / h=127; unconditional to keep
        // the unrolled body straight-line).
        v0.x *= mh0; v0.y *= mh0; v0.z *= mh0; v0.w *= mh0;
        v2.x *= mh2; v2.y *= mh2; v2.z *= mh2; v2.w *= mh2;

        // Own column sums for cols w0..w0+3 (A..D).
        const float cpA = fmaf(2.f, v1.x, v0.x + v2.x);
        const float cmA = v0.x - v2.x;
        const float cyA = fmaf(-4.f, v1.x, cpA);
        const float cpB = fmaf(2.f, v1.y, v0.y + v2.y);
        const float cmB = v0.y - v2.y;
        const float cyB = fmaf(-4.f, v1.y, cpB);
        const float cpC = fmaf(2.f, v1.z, v0.z + v2.z);
        const float cmC = v0.z - v2.z;
        const float cyC = fmaf(-4.f, v1.z, cpC);
        const float cpD = fmaf(2.f, v1.w, v0.w + v2.w);
        const float cmD = v0.w - v2.w;
        const float cyD = fmaf(-4.f, v1.w, cpD);

        // Halo column sums from neighbor lanes (row masks already applied).
        const float cpL = __shfl_up(cpD, 1) * mwA;
        const float cmL = __shfl_up(cmD, 1) * mwA;
        const float cyL = __shfl_up(cyD, 1) * mwA;
        const float cpR = __shfl_down(cpA, 1) * mwB;
        const float cmR = __shfl_down(cmA, 1) * mwB;
        const float cyR = __shfl_down(cyA, 1) * mwB;

        float4 sc;
        sc.x = gca_score16(cpL, cpA, cpB,  cmL, cmA, cmB,  cyL, cyA, cyB);
        sc.y = gca_score16(cpA, cpB, cpC,  cmA, cmB, cmC,  cyA, cyB, cyC);
        sc.z = gca_score16(cpB, cpC, cpD,  cmB, cmC, cmD,  cyB, cyC, cyD);
        sc.w = gca_score16(cpC, cpD, cpR,  cmC, cmD, cmR,  cyC, cyD, cyR);
        s[i] = sc;
        lmax.x = fmaxf(lmax.x, sc.x);
        lmax.y = fmaxf(lmax.y, sc.y);
        lmax.z = fmaxf(lmax.z, sc.z);
        lmax.w = fmaxf(lmax.w, sc.w);
    }

    // Cross-group softmax reduction (per pixel, over the 16 channel groups).
    __shared__ float4 redmax[CGRP][32];
    __shared__ float4 redsum[CGRP][32];

    redmax[ty][tx] = lmax;
    __syncthreads();
    float4 gmax = make_float4(-3.0e38f, -3.0e38f, -3.0e38f, -3.0e38f);
    #pragma unroll
    for (int g = 0; g < CGRP; ++g) {
        const float4 m = redmax[g][tx];
        gmax.x = fmaxf(gmax.x, m.x);
        gmax.y = fmaxf(gmax.y, m.y);
        gmax.z = fmaxf(gmax.z, m.z);
        gmax.w = fmaxf(gmax.w, m.w);
    }

    float4 lsum = make_float4(0.f, 0.f, 0.f, 0.f);
    #pragma unroll
    for (int i = 0; i < CPW; ++i) {
        float4 e;
        e.x = __builtin_amdgcn_exp2f((s[i].x - gmax.x) * GCA_LOG2E);
        e.y = __builtin_amdgcn_exp2f((s[i].y - gmax.y) * GCA_LOG2E);
        e.z = __builtin_amdgcn_exp2f((s[i].z - gmax.z) * GCA_LOG2E);
        e.w = __builtin_amdgcn_exp2f((s[i].w - gmax.w) * GCA_LOG2E);
        s[i] = e;
        lsum.x += e.x; lsum.y += e.y; lsum.z += e.z; lsum.w += e.w;
    }
    redsum[ty][tx] = lsum;
    __syncthreads();
    float4 tot = make_float4(0.f, 0.f, 0.f, 0.f);
    #pragma unroll
    for (int g = 0; g < CGRP; ++g) {
        const float4 sm = redsum[g][tx];
        tot.x += sm.x; tot.y += sm.y; tot.z += sm.z; tot.w += sm.w;
    }
    const float invx = __builtin_amdgcn_rcpf(tot.x);
    const float invy = __builtin_amdgcn_rcpf(tot.y);
    const float invz = __builtin_amdgcn_rcpf(tot.z);
    const float invw = __builtin_amdgcn_rcpf(tot.w);

    // Epilogue: out = (softmax + 1) * x, x from registers; NT stores.
    #pragma unroll
    for (int i = 0; i < CPW; ++i) {
        const float4 xv = xc[i];
        gca_f4 o;
        o.x = fmaf(s[i].x * invx, xv.x, xv.x);
        o.y = fmaf(s[i].y * invy, xv.y, xv.y);
        o.z = fmaf(s[i].z * invz, xv.z, xv.z);
        o.w = fmaf(s[i].w * invw, xv.w, xv.w);
        __builtin_nontemporal_store(o, (gca_f4*)(obase + (size_t)i * plane + r1off));
    }
}

extern "C" void kernel_launch(void* const* d_in, const int* in_sizes, int n_in,
                              void* d_out, int out_size, void* d_ws, size_t ws_size,
                              hipStream_t stream) {
    (void)in_sizes; (void)n_in; (void)d_ws; (void)ws_size; (void)out_size;
    const float* x = (const float*)d_in[0];
    float* out = (float*)d_out;
    dim3 block(32, CGRP, 1);
    dim3 grid(GCA_B * GCA_H, 1, 1);   // 2048 blocks, swizzled in-kernel
    gca_fused16<<<grid, block, 0, stream>>>(x, out);
}

// Round 17
// 56.487 us; speedup vs baseline: 1.3079x; 1.3079x over previous
//
#include <hip/hip_runtime.h>
#include <hip/hip_fp16.h>

// GradientCurvatureAttention: fused depthwise-conv + curvature + channel-softmax + scale.
// x: [B=16, C=128, H=128, W=128] fp32, NCHW. out: same shape.
//
// Round 17: R15 (57.8us) with per-thread state PACKED TO F16: s[16]+xc[16]
// float4 (128 f32 regs) -> __half2 sp[32]+xp[32] (64 regs). Goal: land in the
// <=64-VGPR hardware allocation class (R7/R12/R14 @64 VGPR -> occ 37%; R15
// @100 / R16 @68 -> occ 20-22% - the quantum steps at ~64). Keeps: xc-in-regs,
// NT stores, raw intrinsics, CGRP=8 256-thr blocks, straight-line body.
// Precision: f16 rounding -> absmax ~0.03-0.06 vs threshold 0.205.

#define GCA_B 16
#define GCA_C 128
#define GCA_H 128
#define GCA_W 128
#define CGRP  8            // channel groups (blockDim.y)
#define CPW   (GCA_C/CGRP) // 16 channels per group

#define GCA_LOG2E 1.44269504088896f

typedef float gca_f4 __attribute__((ext_vector_type(4)));  // native vec for NT store

__device__ __forceinline__ float gca_score17(float cpl, float cpc, float cpr,
                                             float cml, float cmc, float cmr,
                                             float cyl, float cyc, float cyr) {
    const float Gx  = cpl - cpr;                       // [1,2,1]v x [1,0,-1]h
    const float Gy  = fmaf(2.f, cmc, cml + cmr);       // [1,0,-1]v x [1,2,1]h
    const float Ixx = fmaf(-2.f, cpc, cpl + cpr);      // [1,2,1]v x [1,-2,1]h
    const float Ixy = cmr - cml;                       // [1,0,-1]v x [-1,0,1]h
    const float Iyy = fmaf(2.f, cyc, cyl + cyr);       // [1,-2,1]v x [1,2,1]h
    const float gy2 = Gy * Gy;
    const float g2e = fmaf(Gx, Gx, gy2 + 1e-6f);
    const float r   = __builtin_amdgcn_rsqf(g2e);      // raw v_rsq_f32
    const float gm  = g2e * r;                         // sqrt(g2e)
    const float t   = Gx * Iyy;
    const float p   = Gy * Ixy;
    const float inner = fmaf(-2.f, p, t);              // Gx*Iyy - 2*Gy*Ixy
    const float q   = gy2 * Ixx;
    const float num = fmaf(Gx, inner, q);
    const float r3  = (r * r) * r;
    return fmaf(num, r3, gm);                          // grad_mag + curvature
}

__global__ __launch_bounds__(256) void gca_fused17(const float* __restrict__ x,
                                                   float* __restrict__ out) {
    const int tx = threadIdx.x;                 // 0..31 : pixel quad, w0 = 4*tx
    const int ty = threadIdx.y;                 // 0..7  : channel group

    // XCD swizzle: 2048 blocks (= B*H, h minor), 256 consecutive ids per XCD.
    const int id  = blockIdx.x;
    const int swz = ((id & 7) << 8) | (id >> 3);
    const int h   = swz & 127;
    const int b   = swz >> 7;

    const int w0 = tx * 4;
    const int c0 = ty * CPW;

    const int hm = (h > 0) ? h - 1 : 0;
    const int hp = (h < GCA_H - 1) ? h + 1 : GCA_H - 1;
    const float mh0 = (h > 0) ? 1.f : 0.f;
    const float mh2 = (h < GCA_H - 1) ? 1.f : 0.f;
    const float mwA = (tx > 0) ? 1.f : 0.f;    // left halo exists
    const float mwB = (tx < 31) ? 1.f : 0.f;   // right halo exists

    const size_t plane = (size_t)GCA_H * GCA_W;
    const float* base = x   + ((size_t)b * GCA_C + c0) * plane;
    float* obase      = out + ((size_t)b * GCA_C + c0) * plane;

    const int r0off = hm * GCA_W + w0;
    const int r1off = h  * GCA_W + w0;
    const int r2off = hp * GCA_W + w0;

    __half2 sp[CPW * 2];                 // packed scores, then packed exp values
    __half2 xp[CPW * 2];                 // packed center row for the epilogue
    float4 lmax = make_float4(-3.0e38f, -3.0e38f, -3.0e38f, -3.0e38f);

    // Pass 1: conv + curvature scores for 4 pixels x 16 channels.
    #pragma unroll
    for (int i = 0; i < CPW; ++i) {
        const float* p = base + (size_t)i * plane;
        float4 v0 = *(const float4*)(p + r0off);
        const float4 v1 = *(const float4*)(p + r1off);
        float4 v2 = *(const float4*)(p + r2off);
        xp[2 * i]     = __floats2half2_rn(v1.x, v1.y);
        xp[2 * i + 1] = __floats2half2_rn(v1.z, v1.w);

        // Row-edge masks (identity except h=0 / h=127; unconditional to keep
        // the unrolled body straight-line).
        v0.x *= mh0; v0.y *= mh0; v0.z *= mh0; v0.w *= mh0;
        v2.x *= mh2; v2.y *= mh2; v2.z *= mh2; v2.w *= mh2;

        // Own column sums for cols w0..w0+3 (A..D).
        const float cpA = fmaf(2.f, v1.x, v0.x + v2.x);
        const float cmA = v0.x - v2.x;
        const float cyA = fmaf(-4.f, v1.x, cpA);
        const float cpB = fmaf(2.f, v1.y, v0.y + v2.y);
        const float cmB = v0.y - v2.y;
        const float cyB = fmaf(-4.f, v1.y, cpB);
        const float cpC = fmaf(2.f, v1.z, v0.z + v2.z);
        const float cmC = v0.z - v2.z;
        const float cyC = fmaf(-4.f, v1.z, cpC);
        const float cpD = fmaf(2.f, v1.w, v0.w + v2.w);
        const float cmD = v0.w - v2.w;
        const float cyD = fmaf(-4.f, v1.w, cpD);

        // Halo column sums from neighbor lanes (row masks already applied).
        const float cpL = __shfl_up(cpD, 1) * mwA;
        const float cmL = __shfl_up(cmD, 1) * mwA;
        const float cyL = __shfl_up(cyD, 1) * mwA;
        const float cpR = __shfl_down(cpA, 1) * mwB;
        const float cmR = __shfl_down(cmA, 1) * mwB;
        const float cyR = __shfl_down(cyA, 1) * mwB;

        float4 sc;
        sc.x = gca_score17(cpL, cpA, cpB,  cmL, cmA, cmB,  cyL, cyA, cyB);
        sc.y = gca_score17(cpA, cpB, cpC,  cmA, cmB, cmC,  cyA, cyB, cyC);
        sc.z = gca_score17(cpB, cpC, cpD,  cmB, cmC, cmD,  cyB, cyC, cyD);
        sc.w = gca_score17(cpC, cpD, cpR,  cmC, cmD, cmR,  cyC, cyD, cyR);
        sp[2 * i]     = __floats2half2_rn(sc.x, sc.y);
        sp[2 * i + 1] = __floats2half2_rn(sc.z, sc.w);
        lmax.x = fmaxf(lmax.x, sc.x);
        lmax.y = fmaxf(lmax.y, sc.y);
        lmax.z = fmaxf(lmax.z, sc.z);
        lmax.w = fmaxf(lmax.w, sc.w);
    }

    // Cross-group softmax reduction (per pixel, over the 8 channel groups).
    __shared__ float4 redmax[CGRP][32];
    __shared__ float4 redsum[CGRP][32];

    redmax[ty][tx] = lmax;
    __syncthreads();
    float4 gmax = make_float4(-3.0e38f, -3.0e38f, -3.0e38f, -3.0e38f);
    #pragma unroll
    for (int g = 0; g < CGRP; ++g) {
        const float4 m = redmax[g][tx];
        gmax.x = fmaxf(gmax.x, m.x);
        gmax.y = fmaxf(gmax.y, m.y);
        gmax.z = fmaxf(gmax.z, m.z);
        gmax.w = fmaxf(gmax.w, m.w);
    }

    float4 lsum = make_float4(0.f, 0.f, 0.f, 0.f);
    #pragma unroll
    for (int i = 0; i < CPW; ++i) {
        const float2 slo = __half22float2(sp[2 * i]);
        const float2 shi = __half22float2(sp[2 * i + 1]);
        float4 e;
        e.x = __builtin_amdgcn_exp2f((slo.x - gmax.x) * GCA_LOG2E);
        e.y = __builtin_amdgcn_exp2f((slo.y - gmax.y) * GCA_LOG2E);
        e.z = __builtin_amdgcn_exp2f((shi.x - gmax.z) * GCA_LOG2E);
        e.w = __builtin_amdgcn_exp2f((shi.y - gmax.w) * GCA_LOG2E);
        sp[2 * i]     = __floats2half2_rn(e.x, e.y);
        sp[2 * i + 1] = __floats2half2_rn(e.z, e.w);
        lsum.x += e.x; lsum.y += e.y; lsum.z += e.z; lsum.w += e.w;
    }
    redsum[ty][tx] = lsum;
    __syncthreads();
    float4 tot = make_float4(0.f, 0.f, 0.f, 0.f);
    #pragma unroll
    for (int g = 0; g < CGRP; ++g) {
        const float4 sm = redsum[g][tx];
        tot.x += sm.x; tot.y += sm.y; tot.z += sm.z; tot.w += sm.w;
    }
    const float invx = __builtin_amdgcn_rcpf(tot.x);
    const float invy = __builtin_amdgcn_rcpf(tot.y);
    const float invz = __builtin_amdgcn_rcpf(tot.z);
    const float invw = __builtin_amdgcn_rcpf(tot.w);

    // Epilogue: out = (softmax + 1) * x, x unpacked from registers; NT stores.
    #pragma unroll
    for (int i = 0; i < CPW; ++i) {
        const float2 elo = __half22float2(sp[2 * i]);
        const float2 ehi = __half22float2(sp[2 * i + 1]);
        const float2 xlo = __half22float2(xp[2 * i]);
        const float2 xhi = __half22float2(xp[2 * i + 1]);
        gca_f4 o;
        o.x = fmaf(elo.x * invx, xlo.x, xlo.x);
        o.y = fmaf(elo.y * invy, xlo.y, xlo.y);
        o.z = fmaf(ehi.x * invz, xhi.x, xhi.x);
        o.w = fmaf(ehi.y * invw, xhi.y, xhi.y);
        __builtin_nontemporal_store(o, (gca_f4*)(obase + (size_t)i * plane + r1off));
    }
}

extern "C" void kernel_launch(void* const* d_in, const int* in_sizes, int n_in,
                              void* d_out, int out_size, void* d_ws, size_t ws_size,
                              hipStream_t stream) {
    (void)in_sizes; (void)n_in; (void)d_ws; (void)ws_size; (void)out_size;
    const float* x = (const float*)d_in[0];
    float* out = (float*)d_out;
    dim3 block(32, CGRP, 1);
    dim3 grid(GCA_B * GCA_H, 1, 1);   // 2048 blocks, swizzled in-kernel
    gca_fused17<<<grid, block, 0, stream>>>(x, out);
}